// Round 15
// baseline (198.789 us; speedup 1.0000x reference)
//
#include <hip/hip_runtime.h>
#include <hip/hip_bf16.h>
#include <string.h>

// Problem constants
#define NROWS    4096
#define NBR      64
#define NODE_DIM 172
#define EDGE_DIM 172
#define TIME_DIM 100
#define OUT_DIM  272
#define KEY_DIM  444          // NODE+EDGE+TIME
#define KPAD     448
#define QK_PAD   320          // OUT_DIM padded; row stride 640B
#define N_HEADS  8
#define HEAD_DIM 34

typedef __attribute__((ext_vector_type(8))) short short8_t;  // 8 bf16 in 4 VGPRs
typedef __attribute__((ext_vector_type(4))) float f32x4;

__device__ inline short f2b(float x) {          // fp32 -> bf16 (RNE)
  unsigned u = __builtin_bit_cast(unsigned, x);
  unsigned r = (u + 0x7fffu + ((u >> 16) & 1u)) >> 16;
  return (short)r;
}

__device__ inline unsigned pk2(float lo, float hi) {  // v_cvt_pk_bf16_f32
  __hip_bfloat162 h = __float22bfloat162_rn(make_float2(lo, hi));
  unsigned u;
  memcpy(&u, &h, 4);
  return u;
}

typedef const __attribute__((address_space(1))) void gv_t;
typedef __attribute__((address_space(3))) void lv_t;
__device__ inline void gld16(const void* g, void* l) {   // async 16B/lane global->LDS
  __builtin_amdgcn_global_load_lds((gv_t*)g, (lv_t*)l, 16, 0, 0);
}

__device__ inline void barrier_lgkm() {   // rule-18-safe LDS-producing barrier
  asm volatile("s_waitcnt lgkmcnt(0)" ::: "memory");
  __builtin_amdgcn_sched_barrier(0);
  __builtin_amdgcn_s_barrier();
}

// Zero cols K0..KP-1 (for out_ln2's bf16 swizzled O tile).
template<int ROWS, int KP, int K0>
__device__ inline void pad_rows(char* A, int t) {
  constexpr int NC8 = (KP - K0) / 4;
  constexpr int LPR = 512 / ROWS;
  int r = t / LPR;
  int j = t % LPR;
  char* Arow = A + r * (2 * KP);
  int swz = (r & 7) << 4;
  uint2 zz; zz.x = 0; zz.y = 0;
  for (int c8 = j; c8 < NC8; c8 += LPR)
    *(uint2*)(Arow + ((2 * K0 + 8 * c8) ^ swz)) = zz;
}

template<int MT, int KP, int NKK>
__device__ inline void gemm_tile(const short* __restrict__ Wrow, const char* A,
                                 int lr, int lk, f32x4* acc) {
#pragma unroll
  for (int kk = 0; kk < NKK; ++kk) {
    short8_t bfrag = *(const short8_t*)(Wrow + lr * KP + kk * 32 + lk * 8);
#pragma unroll
    for (int mt = 0; mt < MT; ++mt) {
      short8_t afrag = *(const short8_t*)(A + (mt * 16 + lr) * (2 * KP) +
                                          ((kk * 64 + lk * 16) ^ ((lr & 7) << 4)));
      acc[mt] = __builtin_amdgcn_mfma_f32_16x16x32_bf16(afrag, bfrag, acc[mt], 0, 0, 0);
    }
  }
}

// ---------------- kernel 0: weight conversion fp32 -> padded bf16 ----------------
__global__ void convert_w(const float* __restrict__ Wkv, const float* __restrict__ Wq,
                          const float* __restrict__ Wo, short* __restrict__ wq_b,
                          short* __restrict__ wo_b, short* __restrict__ wkt,
                          short* __restrict__ wvh) {
  int i = blockIdx.x * 256 + threadIdx.x;
  if (i < OUT_DIM * QK_PAD) {
    int r = i / QK_PAD, c = i - r * QK_PAD;
    wq_b[i] = (c < OUT_DIM) ? f2b(Wq[r * OUT_DIM + c]) : (short)0;
    wo_b[i] = (c < OUT_DIM) ? f2b(Wo[r * OUT_DIM + c]) : (short)0;
  }
  if (i < N_HEADS * 448 * 64) {
    int h = i / 28672;
    int rem = i - h * 28672;
    int n = rem >> 6, d = rem & 63;
    wkt[i] = (n < KEY_DIM && d < HEAD_DIM) ? f2b(Wkv[(h * HEAD_DIM + d) * KEY_DIM + n])
                                           : (short)0;
  }
  if (i < N_HEADS * 48 * 448) {
    int h = i / 21504;
    int rem = i - h * 21504;
    int cp = rem / 448, k = rem - cp * 448;
    wvh[i] = (cp < HEAD_DIM && k < KEY_DIM)
                 ? f2b(Wkv[(OUT_DIM + h * HEAD_DIM + cp) * KEY_DIM + k])
                 : (short)0;
  }
}

// ---------------- kernel 1: Q = R@Wq^T ; Qt = (1/sqrt34) Qh@Wk  (16 rows/block) --------
// NOTE: Qtg rows are now stored PRE-SWIZZLED: row b, head h, col n at byte
//   b*7168 + h*896 + ((2n) ^ (h<<4))   -> attn7's flat DMA lands it ready for A-frag reads.
__global__ __launch_bounds__(512) void q_qt(const float* __restrict__ node_feat,
                                            const float* __restrict__ time_feat,
                                            const short* __restrict__ Wq,
                                            const short* __restrict__ Wkt,
                                            short* __restrict__ Qtg) {
  __shared__ char Rlds[16 * 640];
  __shared__ char Qp[16 * 1024];
  int rb = blockIdx.x * 16, t = threadIdx.x;
  {
    int r = t >> 5, j = t & 31;
    const float4* pn = (const float4*)(node_feat + (size_t)(rb + r) * NODE_DIM);
    const float4* pt = (const float4*)(time_feat + (size_t)(rb + r) * TIME_DIM);
    float4 vn[2], vt4;
    int in_[2], it_;
#pragma unroll
    for (int i = 0; i < 2; ++i) { int f = j + 32 * i; in_[i] = f > 42 ? 42 : f; vn[i] = pn[in_[i]]; }
    it_ = j > 24 ? 24 : j; vt4 = pt[it_];
    char* Arow = Rlds + r * 640;
    int swz = (r & 7) << 4;
#pragma unroll
    for (int i = 0; i < 2; ++i) {
      uint2 w; w.x = pk2(vn[i].x, vn[i].y); w.y = pk2(vn[i].z, vn[i].w);
      *(uint2*)(Arow + ((8 * in_[i]) ^ swz)) = w;
    }
    {
      uint2 w; w.x = pk2(vt4.x, vt4.y); w.y = pk2(vt4.z, vt4.w);
      *(uint2*)(Arow + ((344 + 8 * it_) ^ swz)) = w;
    }
    if (j < 12) { uint2 zz; zz.x = 0; zz.y = 0; *(uint2*)(Arow + ((544 + 8 * j) ^ swz)) = zz; }
  }
  {
    uint4 zz; zz.x = 0; zz.y = 0; zz.z = 0; zz.w = 0;
    for (int i = t; i < 1024; i += 512) ((uint4*)Qp)[i] = zz;
  }
  __syncthreads();
  int wave = t >> 6, lane = t & 63, lr = lane & 15, lk = lane >> 4;
  f32x4 z = {0.f, 0.f, 0.f, 0.f};

  for (int nt = wave; nt < 17; nt += 8) {
    int nb = nt * 16;
    f32x4 acc[1] = {z};
    gemm_tile<1, QK_PAD, QK_PAD / 32>(Wq + nb * QK_PAD, Rlds, lr, lk, acc);
    int c = nb + lr;
    int h = c / HEAD_DIM, d = c - h * HEAD_DIM;
#pragma unroll
    for (int e = 0; e < 4; ++e) {
      int r = lk * 4 + e;
      *(short*)(Qp + r * 1024 + h * 128 + ((2 * d) ^ ((r & 7) << 4))) = f2b(acc[0][e]);
    }
  }
  __syncthreads();

  int h = wave;
  const short* Wh = Wkt + h * 28672;
  for (int nt = 0; nt < 28; ++nt) {
    f32x4 acc = z;
#pragma unroll
    for (int kk = 0; kk < 2; ++kk) {
      short8_t bfrag = *(const short8_t*)(Wh + (nt * 16 + lr) * 64 + kk * 32 + lk * 8);
      short8_t afrag = *(const short8_t*)(Qp + lr * 1024 + h * 128 +
                                          ((kk * 64 + lk * 16) ^ ((lr & 7) << 4)));
      acc = __builtin_amdgcn_mfma_f32_16x16x32_bf16(afrag, bfrag, acc, 0, 0, 0);
    }
#pragma unroll
    for (int e = 0; e < 4; ++e) {
      int n = nt * 16 + lr;
      *(short*)((char*)Qtg + (size_t)(rb + lk * 4 + e) * 7168 + h * 896 +
                ((2 * n) ^ (h << 4))) = f2b(acc[e] * 0.17149858514250882f);
    }
  }
}

// ---------------- kernel 2: attn7 — DMA + counted-vmcnt raw-barrier pipeline ----------
// Chunk = 32 neighbor rows, fp32 flat: node@0 (22x1024), edge@22528 (22x1024),
// time@45056 (13x1024). 64 virtual DMA slots/chunk -> exactly 8 gld16 per wave.
// q 57..63: half==0 -> Qt[b] (7168B, pre-swizzled), half==1 -> dump.
__device__ inline void stage_chunk(const float* __restrict__ nn,
                                   const float* __restrict__ ef,
                                   const float* __restrict__ tf,
                                   const short* __restrict__ Qtg,
                                   int b, int half, char* buf, char* qtslot, char* dump,
                                   int wave, int lane) {
  size_t row0 = (size_t)b * NBR + half * 32;
  const char* nb = (const char*)(nn + row0 * NODE_DIM);
  const char* eb = (const char*)(ef + row0 * EDGE_DIM);
  const char* tb = (const char*)(tf + row0 * TIME_DIM);
  const char* qb = (const char*)Qtg + (size_t)b * 7168;
#pragma unroll
  for (int i = 0; i < 8; ++i) {
    int q = wave * 8 + i;
    if (q < 22) {
      int off = q * 1024 + lane * 16; if (off > 22000) off = 22000;
      gld16(nb + off, buf + q * 1024);
    } else if (q < 44) {
      int off = (q - 22) * 1024 + lane * 16; if (off > 22000) off = 22000;
      gld16(eb + off, buf + 22528 + (q - 22) * 1024);
    } else if (q < 57) {
      int off = (q - 44) * 1024 + lane * 16; if (off > 12784) off = 12784;
      gld16(tb + off, buf + 45056 + (q - 44) * 1024);
    } else {
      int off = (q - 57) * 1024 + lane * 16;
      gld16(qb + off, half == 0 ? (qtslot + (q - 57) * 1024) : dump);
    }
  }
}

__global__ __launch_bounds__(512) void attn7(const float* __restrict__ nn,
                                             const float* __restrict__ ef,
                                             const float* __restrict__ tf,
                                             const int* __restrict__ nbr_mask,
                                             const short* __restrict__ Qtg,
                                             short* __restrict__ Yh2) {
  __shared__ char Zbuf[2][58368];        // 116,736 : fp32 chunk, Ah bf16 overlaid in place
  __shared__ char QtS[2][7168];          //  14,336
  __shared__ char Dump[1024];            //   1,024
  __shared__ float Spart[4][32][8];      //   4,096
  __shared__ char Pb[16 * 64];           //   1,024
  __shared__ float Mh[8], Lh[8], Fh[8];  //      96
  __shared__ int Mlds[1024];             //   4,096  (16 b x 64 mask words)  total ~141K
  int t = threadIdx.x;
  int wave = t >> 6, lane = t & 63, lr = lane & 15, lk = lane >> 4;
  int bbase = blockIdx.x * 16;
  f32x4 z = {0.f, 0.f, 0.f, 0.f};
  f32x4 accY[4] = {z, z, z, z};

  if (t < 256) ((int4*)Mlds)[t] = ((const int4*)(nbr_mask + (size_t)bbase * 64))[t];
  stage_chunk(nn, ef, tf, Qtg, bbase, 0, Zbuf[0], QtS[0], Dump, wave, lane);

  for (int ci = 0; ci < 32; ++ci) {
    int b = bbase + (ci >> 1), half = ci & 1;
    char* cur = Zbuf[ci & 1];

    if (ci < 31) {
      int b2 = bbase + ((ci + 1) >> 1);
      stage_chunk(nn, ef, tf, Qtg, b2, (ci + 1) & 1, Zbuf[(ci + 1) & 1], QtS[b2 & 1],
                  Dump, wave, lane);
      asm volatile("s_waitcnt vmcnt(8) lgkmcnt(0)" ::: "memory");  // my chunk-ci loads done
    } else {
      asm volatile("s_waitcnt vmcnt(0) lgkmcnt(0)" ::: "memory");
    }
    __builtin_amdgcn_sched_barrier(0);
    __builtin_amdgcn_s_barrier();                  // all waves' chunk-ci DMA done

    // ---- convert fp32 chunk -> bf16 swizzled Ah (in place, two-phase) ----
    int r = t >> 4, j = t & 15;                    // 32 rows x 16 lanes
    f32x4 v[7];
#pragma unroll
    for (int i = 0; i < 7; ++i) {
      int k = j * 4 + i * 64;
      int off = (k < 172) ? (r * 688 + 4 * k)
              : (k < 344) ? (22528 + r * 688 + 4 * (k - 172))
                          : (45056 + r * 400 + 4 * (k - 344));
      v[i] = *(const f32x4*)(cur + off);
    }
    if (j == 15) { v[6][0] = 0.f; v[6][1] = 0.f; v[6][2] = 0.f; v[6][3] = 0.f; }
    barrier_lgkm();                                // all fp32 reads drained
    {
      char* Arow = cur + r * 896;
      int swz = (r & 7) << 4;
#pragma unroll
      for (int i = 0; i < 7; ++i) {
        uint2 w; w.x = pk2(v[i][0], v[i][1]); w.y = pk2(v[i][2], v[i][3]);
        *(uint2*)(Arow + ((8 * j + 128 * i) ^ swz)) = w;
      }
    }
    barrier_lgkm();                                // Ah ready

    // ---- scores: D[h][n] over K=448; wave=(nt 0..1, kq 0..3 covering {4,4,3,3} tiles) --
    {
      int ntl = wave & 1, kq = wave >> 1;
      int tb0 = kq < 2 ? kq * 4 : 8 + (kq - 2) * 3;
      int cnt = kq < 2 ? 4 : 3;
      f32x4 acc = z;
      const char* qbase = QtS[b & 1] + (lr & 7) * 896;
      const char* zbase = cur + (ntl * 16 + lr) * 896;
      int swz = (lr & 7) << 4;
      for (int it = 0; it < cnt; ++it) {
        int keb = 2 * ((tb0 + it) * 32 + lk * 8);
        short8_t a = *(const short8_t*)(qbase + (keb ^ swz));
        short8_t bb = *(const short8_t*)(zbase + (keb ^ swz));
        acc = __builtin_amdgcn_mfma_f32_16x16x32_bf16(a, bb, acc, 0, 0, 0);
      }
#pragma unroll
      for (int e = 0; e < 4; ++e) {
        int h = lk * 4 + e;
        if (h < 8) Spart[kq][ntl * 16 + lr][h] = acc[e];
      }
    }
    barrier_lgkm();

    // ---- online softmax: wave h; both 32-lane halves duplicate (benign) ----
    {
      int h = wave, n = lane & 31;
      float s = Spart[0][n][h] + Spart[1][n][h] + Spart[2][n][h] + Spart[3][n][h];
      if (Mlds[(ci >> 1) * 64 + half * 32 + n] == 0) s = -1e10f;
      float m = s;
#pragma unroll
      for (int off = 16; off >= 1; off >>= 1) m = fmaxf(m, __shfl_xor(m, off));
      float mp = (half == 0) ? -3e38f : Mh[h];
      float mn = fmaxf(mp, m);
      float e = __expf(s - mn);
      float sum = e;
#pragma unroll
      for (int off = 16; off >= 1; off >>= 1) sum += __shfl_xor(sum, off);
      float f = __expf(mp - mn);                   // 0 on first half -> resets accY
      if (lane == 0) {
        Lh[h] = (half ? Lh[h] : 0.f) * f + sum;
        Mh[h] = mn;
        Fh[h] = f;
      }
      int off2 = (2 * n) ^ ((h & 3) << 4);
      *(short*)(Pb + h * 64 + off2) = f2b(e);
      *(short*)(Pb + (h + 8) * 64 + off2) = 0;
    }
    barrier_lgkm();

    // ---- Yh accumulate (K=32 over this chunk's rows) + finalize at half==1 ----
    {
      short8_t pa = *(const short8_t*)(Pb + lr * 64 + ((lk * 16) ^ ((lr & 3) << 4)));
#pragma unroll
      for (int s7 = 0; s7 < 4; ++s7) {
        int vt = wave + 8 * s7;
        if (vt < 28) {
          int colb = 2 * (vt * 16 + lr);
          const char* zb_base = cur + (lk * 8) * 896;
          short8_t zb;
#pragma unroll
          for (int jx = 0; jx < 8; ++jx)
            zb[jx] = *(const short*)(zb_base + jx * 896 + (colb ^ (jx << 4)));
#pragma unroll
          for (int e = 0; e < 4; ++e) accY[s7][e] *= Fh[(lk * 4 + e) & 7];
          accY[s7] = __builtin_amdgcn_mfma_f32_16x16x32_bf16(pa, zb, accY[s7], 0, 0, 0);
        }
      }
      if (half == 1 && lk < 2) {
        float inv[4];
#pragma unroll
        for (int e = 0; e < 4; ++e) inv[e] = 1.f / Lh[lk * 4 + e];
#pragma unroll
        for (int s7 = 0; s7 < 4; ++s7) {
          int vt = wave + 8 * s7;
          if (vt < 28) {
            int k = vt * 16 + lr, kk2 = k >> 5, kp = k & 31;
#pragma unroll
            for (int e = 0; e < 4; ++e)
              Yh2[((size_t)((lk * 4 + e) * 14 + kk2) * 4096 + b) * 32 + kp] =
                  f2b(accY[s7][e] * inv[e]);
          }
        }
      }
    }
    __builtin_amdgcn_s_barrier();                  // Ah/Pb consumed; buf reusable
  }
}

// ---------------- kernel 3: O = Yh.Wvh^T ; out = LN(O @ W_O^T + b_O + R)  (16 rows) ----
__global__ __launch_bounds__(512) void out_ln2(const short* __restrict__ Yh2,
                                               const short* __restrict__ Wvh,
                                               const short* __restrict__ Wo,
                                               const float* __restrict__ bO,
                                               const float* __restrict__ node_feat,
                                               const float* __restrict__ time_feat,
                                               const float* __restrict__ gamma,
                                               const float* __restrict__ beta,
                                               float* __restrict__ out) {
  __shared__ char Alds[16 * 640];
  __shared__ float X[16 * 276];
  int rb = blockIdx.x * 16;
  int t = threadIdx.x;
  int wave = t >> 6, lane = t & 63, lr = lane & 15, lk = lane >> 4;
  pad_rows<16, QK_PAD, OUT_DIM>(Alds, t);
  f32x4 z = {0.f, 0.f, 0.f, 0.f};

  for (int p = wave; p < 24; p += 8) {
    int h = p / 3, nt = p - h * 3;
    f32x4 acc = z;
#pragma unroll
    for (int kk = 0; kk < 14; ++kk) {
      short8_t bfrag = *(const short8_t*)(Wvh + h * 21504 + (nt * 16 + lr) * 448 +
                                          kk * 32 + lk * 8);
      short8_t afrag = *(const short8_t*)(
          Yh2 + ((size_t)(h * 14 + kk) * 4096 + rb + lr) * 32 + lk * 8);
      acc = __builtin_amdgcn_mfma_f32_16x16x32_bf16(afrag, bfrag, acc, 0, 0, 0);
    }
    int cl = nt * 16 + lr;
    if (cl < HEAD_DIM) {
      int c = h * HEAD_DIM + cl;
#pragma unroll
      for (int e = 0; e < 4; ++e) {
        int r = lk * 4 + e;
        *(short*)(Alds + r * 640 + ((2 * c) ^ ((r & 7) << 4))) = f2b(acc[e]);
      }
    }
  }
  __syncthreads();

  for (int nt = wave; nt < 17; nt += 8) {
    int nb = nt * 16;
    f32x4 acc[1] = {z};
    gemm_tile<1, QK_PAD, QK_PAD / 32>(Wo + nb * QK_PAD, Alds, lr, lk, acc);
    int c = nb + lr;
    float bo = bO[c];
#pragma unroll
    for (int e = 0; e < 4; ++e) {
      int r = lk * 4 + e;
      int gr = rb + r;
      float Rv = (c < NODE_DIM) ? node_feat[(size_t)gr * NODE_DIM + c]
                                : time_feat[(size_t)gr * TIME_DIM + (c - NODE_DIM)];
      X[r * 276 + c] = acc[0][e] + bo + Rv;
    }
  }
  __syncthreads();

  int row = t >> 5, j = t & 31;
  float s1 = 0.f, s2 = 0.f;
  for (int c = j; c < OUT_DIM; c += 32) {
    float v = X[row * 276 + c];
    s1 += v; s2 += v * v;
  }
#pragma unroll
  for (int off = 16; off >= 1; off >>= 1) {
    s1 += __shfl_xor(s1, off);
    s2 += __shfl_xor(s2, off);
  }
  float mu = s1 * (1.f / OUT_DIM);
  float var = s2 * (1.f / OUT_DIM) - mu * mu;
  float inv = rsqrtf(fmaxf(var, 0.f) + 1e-5f);
  int gr = rb + row;
  for (int c = j; c < OUT_DIM; c += 32) {
    float v = X[row * 276 + c];
    out[(size_t)gr * OUT_DIM + c] = (v - mu) * inv * gamma[c] + beta[c];
  }
}

extern "C" void kernel_launch(void* const* d_in, const int* in_sizes, int n_in,
                              void* d_out, int out_size, void* d_ws, size_t ws_size,
                              hipStream_t stream) {
  const float* node_feat = (const float*)d_in[0];
  const float* time_feat = (const float*)d_in[1];
  const float* edge_feat = (const float*)d_in[2];
  const float* nbr_node  = (const float*)d_in[3];
  const float* nbr_time  = (const float*)d_in[4];
  const int*   nbr_mask  = (const int*)d_in[5];
  const float* W_Q   = (const float*)d_in[6];
  const float* W_KV  = (const float*)d_in[7];
  const float* W_O   = (const float*)d_in[8];
  const float* b_O   = (const float*)d_in[9];
  const float* gamma = (const float*)d_in[10];
  const float* beta  = (const float*)d_in[11];
  float* out = (float*)d_out;
  char* ws = (char*)d_ws;

  // ws layout (requires ~59.9 MB; ws >= 64.8 MB confirmed in round 4):
  short* wq_b = (short*)(ws);                     // 174,080
  short* wo_b = (short*)(ws + 174080);            // -> 348,160
  short* wvh  = (short*)(ws + 348160);            // -> 692,224
  short* wkt  = (short*)(ws + 692224);            // -> 1,150,976
  short* Qtg  = (short*)(ws + 1150976);           // 4096*7168B -> 30,511,104
  short* Yh2  = (short*)(ws + 30511104);          // -> 59,871,232

  convert_w<<<896, 256, 0, stream>>>(W_KV, W_Q, W_O, wq_b, wo_b, wkt, wvh);
  q_qt<<<NROWS / 16, 512, 0, stream>>>(node_feat, time_feat, wq_b, wkt, Qtg);
  attn7<<<256, 512, 0, stream>>>(nbr_node, edge_feat, nbr_time, nbr_mask, Qtg, Yh2);
  out_ln2<<<NROWS / 16, 512, 0, stream>>>(Yh2, wvh, wo_b, b_O, node_feat, time_feat,
                                          gamma, beta, out);
}

// Round 16
// 190.014 us; speedup vs baseline: 1.0462x; 1.0462x over previous
//
#include <hip/hip_runtime.h>
#include <hip/hip_bf16.h>
#include <string.h>

// Problem constants
#define NROWS    4096
#define NBR      64
#define NODE_DIM 172
#define EDGE_DIM 172
#define TIME_DIM 100
#define OUT_DIM  272
#define KEY_DIM  444          // NODE+EDGE+TIME
#define QK_PAD   320          // OUT_DIM padded; row stride 640B
#define N_HEADS  8
#define HEAD_DIM 34

typedef __attribute__((ext_vector_type(8))) short short8_t;  // 8 bf16 in 4 VGPRs
typedef __attribute__((ext_vector_type(4))) float f32x4;

__device__ inline short f2b(float x) {          // fp32 -> bf16 (RNE)
  unsigned u = __builtin_bit_cast(unsigned, x);
  unsigned r = (u + 0x7fffu + ((u >> 16) & 1u)) >> 16;
  return (short)r;
}

__device__ inline unsigned pk2(float lo, float hi) {  // v_cvt_pk_bf16_f32
  __hip_bfloat162 h = __float22bfloat162_rn(make_float2(lo, hi));
  unsigned u;
  memcpy(&u, &h, 4);
  return u;
}

typedef const __attribute__((address_space(1))) void gv_t;
typedef __attribute__((address_space(3))) void lv_t;
__device__ inline void gld16(const void* g, void* l) {   // async 16B/lane global->LDS
  __builtin_amdgcn_global_load_lds((gv_t*)g, (lv_t*)l, 16, 0, 0);
}

// Zero cols K0..KP-1 (for out_ln2's bf16 swizzled O tile).
template<int ROWS, int KP, int K0>
__device__ inline void pad_rows(char* A, int t) {
  constexpr int NC8 = (KP - K0) / 4;
  constexpr int LPR = 512 / ROWS;
  int r = t / LPR;
  int j = t % LPR;
  char* Arow = A + r * (2 * KP);
  int swz = (r & 7) << 4;
  uint2 zz; zz.x = 0; zz.y = 0;
  for (int c8 = j; c8 < NC8; c8 += LPR)
    *(uint2*)(Arow + ((2 * K0 + 8 * c8) ^ swz)) = zz;
}

template<int MT, int KP, int NKK>
__device__ inline void gemm_tile(const short* __restrict__ Wrow, const char* A,
                                 int lr, int lk, f32x4* acc) {
#pragma unroll
  for (int kk = 0; kk < NKK; ++kk) {
    short8_t bfrag = *(const short8_t*)(Wrow + lr * KP + kk * 32 + lk * 8);
#pragma unroll
    for (int mt = 0; mt < MT; ++mt) {
      short8_t afrag = *(const short8_t*)(A + (mt * 16 + lr) * (2 * KP) +
                                          ((kk * 64 + lk * 16) ^ ((lr & 7) << 4)));
      acc[mt] = __builtin_amdgcn_mfma_f32_16x16x32_bf16(afrag, bfrag, acc[mt], 0, 0, 0);
    }
  }
}

// ---------------- kernel 0: weight conversion fp32 -> padded bf16 ----------------
__global__ void convert_w(const float* __restrict__ Wkv, const float* __restrict__ Wq,
                          const float* __restrict__ Wo, short* __restrict__ wq_b,
                          short* __restrict__ wo_b, short* __restrict__ wkt,
                          short* __restrict__ wvh) {
  int i = blockIdx.x * 256 + threadIdx.x;
  if (i < OUT_DIM * QK_PAD) {
    int r = i / QK_PAD, c = i - r * QK_PAD;
    wq_b[i] = (c < OUT_DIM) ? f2b(Wq[r * OUT_DIM + c]) : (short)0;
    wo_b[i] = (c < OUT_DIM) ? f2b(Wo[r * OUT_DIM + c]) : (short)0;
  }
  if (i < N_HEADS * 448 * 64) {
    int h = i / 28672;
    int rem = i - h * 28672;
    int n = rem >> 6, d = rem & 63;
    wkt[i] = (n < KEY_DIM && d < HEAD_DIM) ? f2b(Wkv[(h * HEAD_DIM + d) * KEY_DIM + n])
                                           : (short)0;
  }
  if (i < N_HEADS * 48 * 448) {
    int h = i / 21504;
    int rem = i - h * 21504;
    int cp = rem / 448, k = rem - cp * 448;
    wvh[i] = (cp < HEAD_DIM && k < KEY_DIM)
                 ? f2b(Wkv[(OUT_DIM + h * HEAD_DIM + cp) * KEY_DIM + k])
                 : (short)0;
  }
}

// ---------------- kernel 1: Q = R@Wq^T ; Qt = (1/sqrt34) Qh@Wk  (16 rows/block) --------
__global__ __launch_bounds__(512) void q_qt(const float* __restrict__ node_feat,
                                            const float* __restrict__ time_feat,
                                            const short* __restrict__ Wq,
                                            const short* __restrict__ Wkt,
                                            short* __restrict__ Qtg) {
  __shared__ char Rlds[16 * 640];
  __shared__ char Qp[16 * 1024];
  int rb = blockIdx.x * 16, t = threadIdx.x;
  {
    int r = t >> 5, j = t & 31;
    const float4* pn = (const float4*)(node_feat + (size_t)(rb + r) * NODE_DIM);
    const float4* pt = (const float4*)(time_feat + (size_t)(rb + r) * TIME_DIM);
    float4 vn[2], vt4;
    int in_[2], it_;
#pragma unroll
    for (int i = 0; i < 2; ++i) { int f = j + 32 * i; in_[i] = f > 42 ? 42 : f; vn[i] = pn[in_[i]]; }
    it_ = j > 24 ? 24 : j; vt4 = pt[it_];
    char* Arow = Rlds + r * 640;
    int swz = (r & 7) << 4;
#pragma unroll
    for (int i = 0; i < 2; ++i) {
      uint2 w; w.x = pk2(vn[i].x, vn[i].y); w.y = pk2(vn[i].z, vn[i].w);
      *(uint2*)(Arow + ((8 * in_[i]) ^ swz)) = w;
    }
    {
      uint2 w; w.x = pk2(vt4.x, vt4.y); w.y = pk2(vt4.z, vt4.w);
      *(uint2*)(Arow + ((344 + 8 * it_) ^ swz)) = w;
    }
    if (j < 12) { uint2 zz; zz.x = 0; zz.y = 0; *(uint2*)(Arow + ((544 + 8 * j) ^ swz)) = zz; }
  }
  {
    uint4 zz; zz.x = 0; zz.y = 0; zz.z = 0; zz.w = 0;
    for (int i = t; i < 1024; i += 512) ((uint4*)Qp)[i] = zz;
  }
  __syncthreads();
  int wave = t >> 6, lane = t & 63, lr = lane & 15, lk = lane >> 4;
  f32x4 z = {0.f, 0.f, 0.f, 0.f};

  for (int nt = wave; nt < 17; nt += 8) {
    int nb = nt * 16;
    f32x4 acc[1] = {z};
    gemm_tile<1, QK_PAD, QK_PAD / 32>(Wq + nb * QK_PAD, Rlds, lr, lk, acc);
    int c = nb + lr;
    int h = c / HEAD_DIM, d = c - h * HEAD_DIM;
#pragma unroll
    for (int e = 0; e < 4; ++e) {
      int r = lk * 4 + e;
      *(short*)(Qp + r * 1024 + h * 128 + ((2 * d) ^ ((r & 7) << 4))) = f2b(acc[0][e]);
    }
  }
  __syncthreads();

  int h = wave;
  const short* Wh = Wkt + h * 28672;
  for (int nt = 0; nt < 28; ++nt) {
    f32x4 acc = z;
#pragma unroll
    for (int kk = 0; kk < 2; ++kk) {
      short8_t bfrag = *(const short8_t*)(Wh + (nt * 16 + lr) * 64 + kk * 32 + lk * 8);
      short8_t afrag = *(const short8_t*)(Qp + lr * 1024 + h * 128 +
                                          ((kk * 64 + lk * 16) ^ ((lr & 7) << 4)));
      acc = __builtin_amdgcn_mfma_f32_16x16x32_bf16(afrag, bfrag, acc, 0, 0, 0);
    }
#pragma unroll
    for (int e = 0; e < 4; ++e)
      Qtg[(size_t)(rb + lk * 4 + e) * 3584 + h * 448 + nt * 16 + lr] =
          f2b(acc[e] * 0.17149858514250882f);
  }
}

// ---------------- kernel 2: attn8 — burst-DMA chunked staging at 2 blocks/CU ----------
// One b per block. Two 32-row chunks, single LDS buffer: DMA burst (~7 gld16/wave,
// fire-and-forget) -> __syncthreads (vmcnt(0) drain is wanted here) -> in-place fp32->bf16
// convert -> scores -> online softmax -> Yh accumulate. Cross-block overlap (2 blocks/CU)
// hides the DMA wait. Chunk buffer: node@0 (22x1024), edge@22528 (22x1024), time@45056
// (13x1024) = 58,368 B.
__global__ __launch_bounds__(512) void attn8(const float* __restrict__ nn,
                                             const float* __restrict__ ef,
                                             const float* __restrict__ tf,
                                             const int* __restrict__ nbr_mask,
                                             const short* __restrict__ Qtg,
                                             short* __restrict__ Yh2) {
  __shared__ char Zb[58368];             // fp32 chunk; bf16 Ah overlaid in place (32x896)
  __shared__ float Spart[4][32][8];      // 4,096
  __shared__ char Pb[16 * 64];           // 1,024
  __shared__ float Mh[8], Lh[8], Fh[8];  //    96    total ~63.6 KB -> 2 blocks/CU
  int b = blockIdx.x;
  int t = threadIdx.x;
  int wave = t >> 6, lane = t & 63, lr = lane & 15, lk = lane >> 4;
  f32x4 z = {0.f, 0.f, 0.f, 0.f};
  f32x4 accY[4] = {z, z, z, z};

  int mp0 = nbr_mask[(size_t)b * NBR + (lane & 31)];
  int mp1 = nbr_mask[(size_t)b * NBR + 32 + (lane & 31)];

  for (int half = 0; half < 2; ++half) {
    // ---- burst DMA: 57 slots over 8 waves, all issued back-to-back ----
    {
      size_t row0 = (size_t)b * NBR + half * 32;
      const char* nb = (const char*)(nn + row0 * NODE_DIM);
      const char* eb = (const char*)(ef + row0 * EDGE_DIM);
      const char* tb = (const char*)(tf + row0 * TIME_DIM);
      for (int q = wave; q < 57; q += 8) {
        if (q < 22) {
          int off = q * 1024 + lane * 16; if (off > 22000) off = 22000;
          gld16(nb + off, Zb + q * 1024);
        } else if (q < 44) {
          int off = (q - 22) * 1024 + lane * 16; if (off > 22000) off = 22000;
          gld16(eb + off, Zb + 22528 + (q - 22) * 1024);
        } else {
          int off = (q - 44) * 1024 + lane * 16; if (off > 12784) off = 12784;
          gld16(tb + off, Zb + 45056 + (q - 44) * 1024);
        }
      }
    }
    __syncthreads();                               // vmcnt(0) drain: chunk landed

    // ---- in-place fp32 -> bf16 swizzled Ah (read all, barrier, write) ----
    {
      int r = t >> 4, j = t & 15;                  // 32 rows x 16 lanes
      f32x4 v[7];
#pragma unroll
      for (int i = 0; i < 7; ++i) {
        int k = j * 4 + i * 64;
        int off = (k < 172) ? (r * 688 + 4 * k)
                : (k < 344) ? (22528 + r * 688 + 4 * (k - 172))
                            : (45056 + r * 400 + 4 * (k - 344));
        v[i] = *(const f32x4*)(Zb + off);
      }
      if (j == 15) { v[6][0] = 0.f; v[6][1] = 0.f; v[6][2] = 0.f; v[6][3] = 0.f; }
      __syncthreads();                             // all fp32 reads done
      char* Arow = Zb + r * 896;
      int swz = (r & 7) << 4;
#pragma unroll
      for (int i = 0; i < 7; ++i) {
        uint2 w; w.x = pk2(v[i][0], v[i][1]); w.y = pk2(v[i][2], v[i][3]);
        *(uint2*)(Arow + ((8 * j + 128 * i) ^ swz)) = w;
      }
    }
    __syncthreads();                               // Ah ready

    // ---- scores: D[h][n] over K=448; wave=(ntl 0..1, kq 0..3 tiles {4,4,3,3}) ----
    {
      int ntl = wave & 1, kq = wave >> 1;
      int tb0 = kq < 2 ? kq * 4 : 8 + (kq - 2) * 3;
      int cnt = kq < 2 ? 4 : 3;
      f32x4 acc = z;
      const short* qrow = Qtg + (size_t)b * 3584 + (lr & 7) * 448;
      const char* zbase = Zb + (ntl * 16 + lr) * 896;
      int swz = (lr & 7) << 4;
      for (int it = 0; it < cnt; ++it) {
        int ke = (tb0 + it) * 32 + lk * 8;
        short8_t a = *(const short8_t*)(qrow + ke);
        short8_t bb = *(const short8_t*)(zbase + ((2 * ke) ^ swz));
        acc = __builtin_amdgcn_mfma_f32_16x16x32_bf16(a, bb, acc, 0, 0, 0);
      }
#pragma unroll
      for (int e = 0; e < 4; ++e) {
        int h = lk * 4 + e;
        if (h < 8) Spart[kq][ntl * 16 + lr][h] = acc[e];
      }
    }
    __syncthreads();

    // ---- online softmax: wave h; both 32-lane halves duplicate (benign) ----
    {
      int h = wave, n = lane & 31;
      float s = Spart[0][n][h] + Spart[1][n][h] + Spart[2][n][h] + Spart[3][n][h];
      int mw = (half == 0) ? mp0 : mp1;
      if (mw == 0) s = -1e10f;
      float m = s;
#pragma unroll
      for (int off = 16; off >= 1; off >>= 1) m = fmaxf(m, __shfl_xor(m, off));
      float mp = (half == 0) ? -3e38f : Mh[h];
      float mn = fmaxf(mp, m);
      float e = __expf(s - mn);
      float sum = e;
#pragma unroll
      for (int off = 16; off >= 1; off >>= 1) sum += __shfl_xor(sum, off);
      float f = __expf(mp - mn);                   // 0 on first half -> resets accY
      if (lane == 0) {
        Lh[h] = (half ? Lh[h] : 0.f) * f + sum;
        Mh[h] = mn;
        Fh[h] = f;
      }
      int off2 = (2 * n) ^ ((h & 3) << 4);
      *(short*)(Pb + h * 64 + off2) = f2b(e);
      *(short*)(Pb + (h + 8) * 64 + off2) = 0;
    }
    __syncthreads();

    // ---- Yh accumulate (K=32 rows of this chunk); finalize after half 1 ----
    {
      short8_t pa = *(const short8_t*)(Pb + lr * 64 + ((lk * 16) ^ ((lr & 3) << 4)));
#pragma unroll
      for (int s7 = 0; s7 < 4; ++s7) {
        int vt = wave + 8 * s7;
        if (vt < 28) {
          int colb = 2 * (vt * 16 + lr);
          const char* zb_base = Zb + (lk * 8) * 896;
          short8_t zbv;
#pragma unroll
          for (int jx = 0; jx < 8; ++jx)
            zbv[jx] = *(const short*)(zb_base + jx * 896 + (colb ^ (jx << 4)));
#pragma unroll
          for (int e = 0; e < 4; ++e) accY[s7][e] *= Fh[(lk * 4 + e) & 7];
          accY[s7] = __builtin_amdgcn_mfma_f32_16x16x32_bf16(pa, zbv, accY[s7], 0, 0, 0);
        }
      }
    }
    __syncthreads();                               // Zb consumed; next chunk may overwrite
  }

  if (lk < 2) {                                    // finalize: divide by Lh, write Yh2
    float inv[4];
#pragma unroll
    for (int e = 0; e < 4; ++e) inv[e] = 1.f / Lh[lk * 4 + e];
#pragma unroll
    for (int s7 = 0; s7 < 4; ++s7) {
      int vt = wave + 8 * s7;
      if (vt < 28) {
        int k = vt * 16 + lr, kk2 = k >> 5, kp = k & 31;
#pragma unroll
        for (int e = 0; e < 4; ++e)
          Yh2[((size_t)((lk * 4 + e) * 14 + kk2) * 4096 + b) * 32 + kp] =
              f2b(accY[s7][e] * inv[e]);
      }
    }
  }
}

// ---------------- kernel 3: O = Yh.Wvh^T ; out = LN(O @ W_O^T + b_O + R)  (16 rows) ----
__global__ __launch_bounds__(512) void out_ln2(const short* __restrict__ Yh2,
                                               const short* __restrict__ Wvh,
                                               const short* __restrict__ Wo,
                                               const float* __restrict__ bO,
                                               const float* __restrict__ node_feat,
                                               const float* __restrict__ time_feat,
                                               const float* __restrict__ gamma,
                                               const float* __restrict__ beta,
                                               float* __restrict__ out) {
  __shared__ char Alds[16 * 640];
  __shared__ float X[16 * 276];
  int rb = blockIdx.x * 16;
  int t = threadIdx.x;
  int wave = t >> 6, lane = t & 63, lr = lane & 15, lk = lane >> 4;
  pad_rows<16, QK_PAD, OUT_DIM>(Alds, t);
  f32x4 z = {0.f, 0.f, 0.f, 0.f};

  for (int p = wave; p < 24; p += 8) {
    int h = p / 3, nt = p - h * 3;
    f32x4 acc = z;
#pragma unroll
    for (int kk = 0; kk < 14; ++kk) {
      short8_t bfrag = *(const short8_t*)(Wvh + h * 21504 + (nt * 16 + lr) * 448 +
                                          kk * 32 + lk * 8);
      short8_t afrag = *(const short8_t*)(
          Yh2 + ((size_t)(h * 14 + kk) * 4096 + rb + lr) * 32 + lk * 8);
      acc = __builtin_amdgcn_mfma_f32_16x16x32_bf16(afrag, bfrag, acc, 0, 0, 0);
    }
    int cl = nt * 16 + lr;
    if (cl < HEAD_DIM) {
      int c = h * HEAD_DIM + cl;
#pragma unroll
      for (int e = 0; e < 4; ++e) {
        int r = lk * 4 + e;
        *(short*)(Alds + r * 640 + ((2 * c) ^ ((r & 7) << 4))) = f2b(acc[e]);
      }
    }
  }
  __syncthreads();

  for (int nt = wave; nt < 17; nt += 8) {
    int nb = nt * 16;
    f32x4 acc[1] = {z};
    gemm_tile<1, QK_PAD, QK_PAD / 32>(Wo + nb * QK_PAD, Alds, lr, lk, acc);
    int c = nb + lr;
    float bo = bO[c];
#pragma unroll
    for (int e = 0; e < 4; ++e) {
      int r = lk * 4 + e;
      int gr = rb + r;
      float Rv = (c < NODE_DIM) ? node_feat[(size_t)gr * NODE_DIM + c]
                                : time_feat[(size_t)gr * TIME_DIM + (c - NODE_DIM)];
      X[r * 276 + c] = acc[0][e] + bo + Rv;
    }
  }
  __syncthreads();

  int row = t >> 5, j = t & 31;
  float s1 = 0.f, s2 = 0.f;
  for (int c = j; c < OUT_DIM; c += 32) {
    float v = X[row * 276 + c];
    s1 += v; s2 += v * v;
  }
#pragma unroll
  for (int off = 16; off >= 1; off >>= 1) {
    s1 += __shfl_xor(s1, off);
    s2 += __shfl_xor(s2, off);
  }
  float mu = s1 * (1.f / OUT_DIM);
  float var = s2 * (1.f / OUT_DIM) - mu * mu;
  float inv = rsqrtf(fmaxf(var, 0.f) + 1e-5f);
  int gr = rb + row;
  for (int c = j; c < OUT_DIM; c += 32) {
    float v = X[row * 276 + c];
    out[(size_t)gr * OUT_DIM + c] = (v - mu) * inv * gamma[c] + beta[c];
  }
}

extern "C" void kernel_launch(void* const* d_in, const int* in_sizes, int n_in,
                              void* d_out, int out_size, void* d_ws, size_t ws_size,
                              hipStream_t stream) {
  const float* node_feat = (const float*)d_in[0];
  const float* time_feat = (const float*)d_in[1];
  const float* edge_feat = (const float*)d_in[2];
  const float* nbr_node  = (const float*)d_in[3];
  const float* nbr_time  = (const float*)d_in[4];
  const int*   nbr_mask  = (const int*)d_in[5];
  const float* W_Q   = (const float*)d_in[6];
  const float* W_KV  = (const float*)d_in[7];
  const float* W_O   = (const float*)d_in[8];
  const float* b_O   = (const float*)d_in[9];
  const float* gamma = (const float*)d_in[10];
  const float* beta  = (const float*)d_in[11];
  float* out = (float*)d_out;
  char* ws = (char*)d_ws;

  // ws layout (requires ~59.9 MB; ws >= 64.8 MB confirmed in round 4):
  short* wq_b = (short*)(ws);                     // 174,080
  short* wo_b = (short*)(ws + 174080);            // -> 348,160
  short* wvh  = (short*)(ws + 348160);            // -> 692,224
  short* wkt  = (short*)(ws + 692224);            // -> 1,150,976
  short* Qtg  = (short*)(ws + 1150976);           // 4096*3584*2 -> 30,511,104
  short* Yh2  = (short*)(ws + 30511104);          // -> 59,871,232

  convert_w<<<896, 256, 0, stream>>>(W_KV, W_Q, W_O, wq_b, wo_b, wkt, wvh);
  q_qt<<<NROWS / 16, 512, 0, stream>>>(node_feat, time_feat, wq_b, wkt, Qtg);
  attn8<<<NROWS, 512, 0, stream>>>(nbr_node, edge_feat, nbr_time, nbr_mask, Qtg, Yh2);
  out_ln2<<<NROWS / 16, 512, 0, stream>>>(Yh2, wvh, wo_b, b_O, node_feat, time_feat,
                                          gamma, beta, out);
}

// Round 17
// 187.883 us; speedup vs baseline: 1.0580x; 1.0113x over previous
//
#include <hip/hip_runtime.h>
#include <hip/hip_bf16.h>
#include <string.h>

// Problem constants
#define NROWS    4096
#define NBR      64
#define NODE_DIM 172
#define EDGE_DIM 172
#define TIME_DIM 100
#define OUT_DIM  272
#define KEY_DIM  444          // NODE+EDGE+TIME
#define QK_PAD   320          // OUT_DIM padded; row stride 640B
#define N_HEADS  8
#define HEAD_DIM 34

typedef __attribute__((ext_vector_type(8))) short short8_t;  // 8 bf16 in 4 VGPRs
typedef __attribute__((ext_vector_type(4))) float f32x4;

__device__ inline short f2b(float x) {          // fp32 -> bf16 (RNE)
  unsigned u = __builtin_bit_cast(unsigned, x);
  unsigned r = (u + 0x7fffu + ((u >> 16) & 1u)) >> 16;
  return (short)r;
}

__device__ inline unsigned pk2(float lo, float hi) {  // v_cvt_pk_bf16_f32
  __hip_bfloat162 h = __float22bfloat162_rn(make_float2(lo, hi));
  unsigned u;
  memcpy(&u, &h, 4);
  return u;
}

// Zero cols K0..KP-1 (for out_ln2's bf16 swizzled O tile).
template<int ROWS, int KP, int K0>
__device__ inline void pad_rows(char* A, int t) {
  constexpr int NC8 = (KP - K0) / 4;
  constexpr int LPR = 512 / ROWS;
  int r = t / LPR;
  int j = t % LPR;
  char* Arow = A + r * (2 * KP);
  int swz = (r & 7) << 4;
  uint2 zz; zz.x = 0; zz.y = 0;
  for (int c8 = j; c8 < NC8; c8 += LPR)
    *(uint2*)(Arow + ((2 * K0 + 8 * c8) ^ swz)) = zz;
}

template<int MT, int KP, int NKK>
__device__ inline void gemm_tile(const short* __restrict__ Wrow, const char* A,
                                 int lr, int lk, f32x4* acc) {
#pragma unroll
  for (int kk = 0; kk < NKK; ++kk) {
    short8_t bfrag = *(const short8_t*)(Wrow + lr * KP + kk * 32 + lk * 8);
#pragma unroll
    for (int mt = 0; mt < MT; ++mt) {
      short8_t afrag = *(const short8_t*)(A + (mt * 16 + lr) * (2 * KP) +
                                          ((kk * 64 + lk * 16) ^ ((lr & 7) << 4)));
      acc[mt] = __builtin_amdgcn_mfma_f32_16x16x32_bf16(afrag, bfrag, acc[mt], 0, 0, 0);
    }
  }
}

// ---------------- kernel 0: weight conversion fp32 -> padded bf16 ----------------
__global__ void convert_w(const float* __restrict__ Wkv, const float* __restrict__ Wq,
                          const float* __restrict__ Wo, short* __restrict__ wq_b,
                          short* __restrict__ wo_b, short* __restrict__ wkt,
                          short* __restrict__ wvh) {
  int i = blockIdx.x * 256 + threadIdx.x;
  if (i < OUT_DIM * QK_PAD) {
    int r = i / QK_PAD, c = i - r * QK_PAD;
    wq_b[i] = (c < OUT_DIM) ? f2b(Wq[r * OUT_DIM + c]) : (short)0;
    wo_b[i] = (c < OUT_DIM) ? f2b(Wo[r * OUT_DIM + c]) : (short)0;
  }
  if (i < N_HEADS * 448 * 64) {
    int h = i / 28672;
    int rem = i - h * 28672;
    int n = rem >> 6, d = rem & 63;
    wkt[i] = (n < KEY_DIM && d < HEAD_DIM) ? f2b(Wkv[(h * HEAD_DIM + d) * KEY_DIM + n])
                                           : (short)0;
  }
  if (i < N_HEADS * 48 * 448) {
    int h = i / 21504;
    int rem = i - h * 21504;
    int cp = rem / 448, k = rem - cp * 448;
    wvh[i] = (cp < HEAD_DIM && k < KEY_DIM)
                 ? f2b(Wkv[(OUT_DIM + h * HEAD_DIM + cp) * KEY_DIM + k])
                 : (short)0;
  }
}

// ---------------- kernel 1: Q = R@Wq^T ; Qt = (1/sqrt34) Qh@Wk  (16 rows/block) --------
__global__ __launch_bounds__(512) void q_qt(const float* __restrict__ node_feat,
                                            const float* __restrict__ time_feat,
                                            const short* __restrict__ Wq,
                                            const short* __restrict__ Wkt,
                                            short* __restrict__ Qtg) {
  __shared__ char Rlds[16 * 640];
  __shared__ char Qp[16 * 1024];
  int rb = blockIdx.x * 16, t = threadIdx.x;
  {
    int r = t >> 5, j = t & 31;
    const float4* pn = (const float4*)(node_feat + (size_t)(rb + r) * NODE_DIM);
    const float4* pt = (const float4*)(time_feat + (size_t)(rb + r) * TIME_DIM);
    float4 vn[2], vt4;
    int in_[2], it_;
#pragma unroll
    for (int i = 0; i < 2; ++i) { int f = j + 32 * i; in_[i] = f > 42 ? 42 : f; vn[i] = pn[in_[i]]; }
    it_ = j > 24 ? 24 : j; vt4 = pt[it_];
    char* Arow = Rlds + r * 640;
    int swz = (r & 7) << 4;
#pragma unroll
    for (int i = 0; i < 2; ++i) {
      uint2 w; w.x = pk2(vn[i].x, vn[i].y); w.y = pk2(vn[i].z, vn[i].w);
      *(uint2*)(Arow + ((8 * in_[i]) ^ swz)) = w;
    }
    {
      uint2 w; w.x = pk2(vt4.x, vt4.y); w.y = pk2(vt4.z, vt4.w);
      *(uint2*)(Arow + ((344 + 8 * it_) ^ swz)) = w;
    }
    if (j < 12) { uint2 zz; zz.x = 0; zz.y = 0; *(uint2*)(Arow + ((544 + 8 * j) ^ swz)) = zz; }
  }
  {
    uint4 zz; zz.x = 0; zz.y = 0; zz.z = 0; zz.w = 0;
    for (int i = t; i < 1024; i += 512) ((uint4*)Qp)[i] = zz;
  }
  __syncthreads();
  int wave = t >> 6, lane = t & 63, lr = lane & 15, lk = lane >> 4;
  f32x4 z = {0.f, 0.f, 0.f, 0.f};

  for (int nt = wave; nt < 17; nt += 8) {
    int nb = nt * 16;
    f32x4 acc[1] = {z};
    gemm_tile<1, QK_PAD, QK_PAD / 32>(Wq + nb * QK_PAD, Rlds, lr, lk, acc);
    int c = nb + lr;
    int h = c / HEAD_DIM, d = c - h * HEAD_DIM;
#pragma unroll
    for (int e = 0; e < 4; ++e) {
      int r = lk * 4 + e;
      *(short*)(Qp + r * 1024 + h * 128 + ((2 * d) ^ ((r & 7) << 4))) = f2b(acc[0][e]);
    }
  }
  __syncthreads();

  int h = wave;
  const short* Wh = Wkt + h * 28672;
  for (int nt = 0; nt < 28; ++nt) {
    f32x4 acc = z;
#pragma unroll
    for (int kk = 0; kk < 2; ++kk) {
      short8_t bfrag = *(const short8_t*)(Wh + (nt * 16 + lr) * 64 + kk * 32 + lk * 8);
      short8_t afrag = *(const short8_t*)(Qp + lr * 1024 + h * 128 +
                                          ((kk * 64 + lk * 16) ^ ((lr & 7) << 4)));
      acc = __builtin_amdgcn_mfma_f32_16x16x32_bf16(afrag, bfrag, acc, 0, 0, 0);
    }
#pragma unroll
    for (int e = 0; e < 4; ++e)
      Qtg[(size_t)(rb + lk * 4 + e) * 3584 + h * 448 + nt * 16 + lr] =
          f2b(acc[e] * 0.17149858514250882f);
  }
}

// ---------------- kernel 2: attn9 — 2x32-row chunks, reg-staged, 4 blocks/CU ----------
// LDS = 28,672 (Zb) + 4,096 (Spart) + 1,024 (Pb) + 96 = 33,888 B -> 4 blocks/CU at
// VGPR<=64. Online softmax across the two chunks (attn8-proven math); staging is the
// attn3-proven reg->bf16->swizzled-LDS pattern at 16 lanes/row.
__global__ __launch_bounds__(512) void attn9(const float* __restrict__ nn,
                                             const float* __restrict__ ef,
                                             const float* __restrict__ tf,
                                             const int* __restrict__ nbr_mask,
                                             const short* __restrict__ Qtg,
                                             short* __restrict__ Yh2) {
  __shared__ char Zb[32 * 896];          // 28,672 : chunk Z bf16 swizzled
  __shared__ float Spart[4][32][8];      //  4,096
  __shared__ char Pb[16 * 64];           //  1,024
  __shared__ float Mh[8], Lh[8], Fh[8];  //     96
  int b = blockIdx.x;
  int t = threadIdx.x;
  int wave = t >> 6, lane = t & 63, lr = lane & 15, lk = lane >> 4;
  f32x4 z = {0.f, 0.f, 0.f, 0.f};
  f32x4 accY[4] = {z, z, z, z};

  int mp0 = nbr_mask[(size_t)b * NBR + (lane & 31)];
  int mp1 = nbr_mask[(size_t)b * NBR + 32 + (lane & 31)];

  for (int half = 0; half < 2; ++half) {
    // ---- stage 32 rows: 16 lanes/row, clamped uniform trips, reg->bf16->LDS ----
    {
      int r = t >> 4, j = t & 15;
      size_t row0 = (size_t)b * NBR + half * 32 + r;
      const float4* pn = (const float4*)(nn + row0 * NODE_DIM);
      const float4* pe = (const float4*)(ef + row0 * EDGE_DIM);
      const float4* pt = (const float4*)(tf + row0 * TIME_DIM);
      float4 vn[3], ve[3], vt4[2];
      int in_[3], it_[2];
#pragma unroll
      for (int i = 0; i < 3; ++i) { int f = j + 16 * i; in_[i] = f > 42 ? 42 : f; vn[i] = pn[in_[i]]; }
#pragma unroll
      for (int i = 0; i < 3; ++i) { ve[i] = pe[in_[i]]; }
#pragma unroll
      for (int i = 0; i < 2; ++i) { int f = j + 16 * i; it_[i] = f > 24 ? 24 : f; vt4[i] = pt[it_[i]]; }
      char* Arow = Zb + r * 896;
      int swz = (r & 7) << 4;
#pragma unroll
      for (int i = 0; i < 3; ++i) {
        uint2 w; w.x = pk2(vn[i].x, vn[i].y); w.y = pk2(vn[i].z, vn[i].w);
        *(uint2*)(Arow + ((8 * in_[i]) ^ swz)) = w;
      }
#pragma unroll
      for (int i = 0; i < 3; ++i) {
        uint2 w; w.x = pk2(ve[i].x, ve[i].y); w.y = pk2(ve[i].z, ve[i].w);
        *(uint2*)(Arow + ((344 + 8 * in_[i]) ^ swz)) = w;
      }
#pragma unroll
      for (int i = 0; i < 2; ++i) {
        uint2 w; w.x = pk2(vt4[i].x, vt4[i].y); w.y = pk2(vt4[i].z, vt4[i].w);
        *(uint2*)(Arow + ((688 + 8 * it_[i]) ^ swz)) = w;
      }
      if (j == 0) { uint2 zz; zz.x = 0; zz.y = 0; *(uint2*)(Arow + (888 ^ swz)) = zz; }
    }
    __syncthreads();

    // ---- scores: D[h][n] over K=448; wave=(ntl 0..1, kq 0..3 tiles {4,4,3,3}) ----
    {
      int ntl = wave & 1, kq = wave >> 1;
      int tb0 = kq < 2 ? kq * 4 : 8 + (kq - 2) * 3;
      int cnt = kq < 2 ? 4 : 3;
      f32x4 acc = z;
      const short* qrow = Qtg + (size_t)b * 3584 + (lr & 7) * 448;
      const char* zbase = Zb + (ntl * 16 + lr) * 896;
      int swz = (lr & 7) << 4;
      for (int it = 0; it < cnt; ++it) {
        int ke = (tb0 + it) * 32 + lk * 8;
        short8_t a = *(const short8_t*)(qrow + ke);
        short8_t bb = *(const short8_t*)(zbase + ((2 * ke) ^ swz));
        acc = __builtin_amdgcn_mfma_f32_16x16x32_bf16(a, bb, acc, 0, 0, 0);
      }
#pragma unroll
      for (int e = 0; e < 4; ++e) {
        int h = lk * 4 + e;
        if (h < 8) Spart[kq][ntl * 16 + lr][h] = acc[e];
      }
    }
    __syncthreads();

    // ---- online softmax: wave h; both 32-lane halves duplicate (benign) ----
    {
      int h = wave, n = lane & 31;
      float s = Spart[0][n][h] + Spart[1][n][h] + Spart[2][n][h] + Spart[3][n][h];
      int mw = (half == 0) ? mp0 : mp1;
      if (mw == 0) s = -1e10f;
      float m = s;
#pragma unroll
      for (int off = 16; off >= 1; off >>= 1) m = fmaxf(m, __shfl_xor(m, off));
      float mp = (half == 0) ? -3e38f : Mh[h];
      float mn = fmaxf(mp, m);
      float e = __expf(s - mn);
      float sum = e;
#pragma unroll
      for (int off = 16; off >= 1; off >>= 1) sum += __shfl_xor(sum, off);
      float f = __expf(mp - mn);                   // 0 on first half -> resets accY
      if (lane == 0) {
        Lh[h] = (half ? Lh[h] : 0.f) * f + sum;
        Mh[h] = mn;
        Fh[h] = f;
      }
      int off2 = (2 * n) ^ ((h & 3) << 4);
      *(short*)(Pb + h * 64 + off2) = f2b(e);
      *(short*)(Pb + (h + 8) * 64 + off2) = 0;
    }
    __syncthreads();

    // ---- Yh accumulate (K=32 rows of this chunk) ----
    {
      short8_t pa = *(const short8_t*)(Pb + lr * 64 + ((lk * 16) ^ ((lr & 3) << 4)));
#pragma unroll
      for (int s7 = 0; s7 < 4; ++s7) {
        int vt = wave + 8 * s7;
        if (vt < 28) {
          int colb = 2 * (vt * 16 + lr);
          const char* zb_base = Zb + (lk * 8) * 896;
          short8_t zbv;
#pragma unroll
          for (int jx = 0; jx < 8; ++jx)
            zbv[jx] = *(const short*)(zb_base + jx * 896 + (colb ^ (jx << 4)));
#pragma unroll
          for (int e = 0; e < 4; ++e) accY[s7][e] *= Fh[(lk * 4 + e) & 7];
          accY[s7] = __builtin_amdgcn_mfma_f32_16x16x32_bf16(pa, zbv, accY[s7], 0, 0, 0);
        }
      }
    }
    __syncthreads();                               // Zb consumed; next chunk may overwrite
  }

  if (lk < 2) {                                    // finalize: divide by Lh, write Yh2
    float inv[4];
#pragma unroll
    for (int e = 0; e < 4; ++e) inv[e] = 1.f / Lh[lk * 4 + e];
#pragma unroll
    for (int s7 = 0; s7 < 4; ++s7) {
      int vt = wave + 8 * s7;
      if (vt < 28) {
        int k = vt * 16 + lr, kk2 = k >> 5, kp = k & 31;
#pragma unroll
        for (int e = 0; e < 4; ++e)
          Yh2[((size_t)((lk * 4 + e) * 14 + kk2) * 4096 + b) * 32 + kp] =
              f2b(accY[s7][e] * inv[e]);
      }
    }
  }
}

// ---------------- kernel 3: O = Yh.Wvh^T ; out = LN(O @ W_O^T + b_O + R)  (16 rows) ----
__global__ __launch_bounds__(512) void out_ln2(const short* __restrict__ Yh2,
                                               const short* __restrict__ Wvh,
                                               const short* __restrict__ Wo,
                                               const float* __restrict__ bO,
                                               const float* __restrict__ node_feat,
                                               const float* __restrict__ time_feat,
                                               const float* __restrict__ gamma,
                                               const float* __restrict__ beta,
                                               float* __restrict__ out) {
  __shared__ char Alds[16 * 640];
  __shared__ float X[16 * 276];
  int rb = blockIdx.x * 16;
  int t = threadIdx.x;
  int wave = t >> 6, lane = t & 63, lr = lane & 15, lk = lane >> 4;
  pad_rows<16, QK_PAD, OUT_DIM>(Alds, t);
  f32x4 z = {0.f, 0.f, 0.f, 0.f};

  for (int p = wave; p < 24; p += 8) {
    int h = p / 3, nt = p - h * 3;
    f32x4 acc = z;
#pragma unroll
    for (int kk = 0; kk < 14; ++kk) {
      short8_t bfrag = *(const short8_t*)(Wvh + h * 21504 + (nt * 16 + lr) * 448 +
                                          kk * 32 + lk * 8);
      short8_t afrag = *(const short8_t*)(
          Yh2 + ((size_t)(h * 14 + kk) * 4096 + rb + lr) * 32 + lk * 8);
      acc = __builtin_amdgcn_mfma_f32_16x16x32_bf16(afrag, bfrag, acc, 0, 0, 0);
    }
    int cl = nt * 16 + lr;
    if (cl < HEAD_DIM) {
      int c = h * HEAD_DIM + cl;
#pragma unroll
      for (int e = 0; e < 4; ++e) {
        int r = lk * 4 + e;
        *(short*)(Alds + r * 640 + ((2 * c) ^ ((r & 7) << 4))) = f2b(acc[e]);
      }
    }
  }
  __syncthreads();

  for (int nt = wave; nt < 17; nt += 8) {
    int nb = nt * 16;
    f32x4 acc[1] = {z};
    gemm_tile<1, QK_PAD, QK_PAD / 32>(Wo + nb * QK_PAD, Alds, lr, lk, acc);
    int c = nb + lr;
    float bo = bO[c];
#pragma unroll
    for (int e = 0; e < 4; ++e) {
      int r = lk * 4 + e;
      int gr = rb + r;
      float Rv = (c < NODE_DIM) ? node_feat[(size_t)gr * NODE_DIM + c]
                                : time_feat[(size_t)gr * TIME_DIM + (c - NODE_DIM)];
      X[r * 276 + c] = acc[0][e] + bo + Rv;
    }
  }
  __syncthreads();

  int row = t >> 5, j = t & 31;
  float s1 = 0.f, s2 = 0.f;
  for (int c = j; c < OUT_DIM; c += 32) {
    float v = X[row * 276 + c];
    s1 += v; s2 += v * v;
  }
#pragma unroll
  for (int off = 16; off >= 1; off >>= 1) {
    s1 += __shfl_xor(s1, off);
    s2 += __shfl_xor(s2, off);
  }
  float mu = s1 * (1.f / OUT_DIM);
  float var = s2 * (1.f / OUT_DIM) - mu * mu;
  float inv = rsqrtf(fmaxf(var, 0.f) + 1e-5f);
  int gr = rb + row;
  for (int c = j; c < OUT_DIM; c += 32) {
    float v = X[row * 276 + c];
    out[(size_t)gr * OUT_DIM + c] = (v - mu) * inv * gamma[c] + beta[c];
  }
}

extern "C" void kernel_launch(void* const* d_in, const int* in_sizes, int n_in,
                              void* d_out, int out_size, void* d_ws, size_t ws_size,
                              hipStream_t stream) {
  const float* node_feat = (const float*)d_in[0];
  const float* time_feat = (const float*)d_in[1];
  const float* edge_feat = (const float*)d_in[2];
  const float* nbr_node  = (const float*)d_in[3];
  const float* nbr_time  = (const float*)d_in[4];
  const int*   nbr_mask  = (const int*)d_in[5];
  const float* W_Q   = (const float*)d_in[6];
  const float* W_KV  = (const float*)d_in[7];
  const float* W_O   = (const float*)d_in[8];
  const float* b_O   = (const float*)d_in[9];
  const float* gamma = (const float*)d_in[10];
  const float* beta  = (const float*)d_in[11];
  float* out = (float*)d_out;
  char* ws = (char*)d_ws;

  // ws layout (requires ~59.9 MB; ws >= 64.8 MB confirmed in round 4):
  short* wq_b = (short*)(ws);                     // 174,080
  short* wo_b = (short*)(ws + 174080);            // -> 348,160
  short* wvh  = (short*)(ws + 348160);            // -> 692,224
  short* wkt  = (short*)(ws + 692224);            // -> 1,150,976
  short* Qtg  = (short*)(ws + 1150976);           // 4096*3584*2 -> 30,511,104
  short* Yh2  = (short*)(ws + 30511104);          // -> 59,871,232

  convert_w<<<896, 256, 0, stream>>>(W_KV, W_Q, W_O, wq_b, wo_b, wkt, wvh);
  q_qt<<<NROWS / 16, 512, 0, stream>>>(node_feat, time_feat, wq_b, wkt, Qtg);
  attn9<<<NROWS, 512, 0, stream>>>(nbr_node, edge_feat, nbr_time, nbr_mask, Qtg, Yh2);
  out_ln2<<<NROWS / 16, 512, 0, stream>>>(Yh2, wvh, wo_b, b_O, node_feat, time_feat,
                                          gamma, beta, out);
}

// Round 18
// 165.233 us; speedup vs baseline: 1.2031x; 1.1371x over previous
//
#include <hip/hip_runtime.h>
#include <hip/hip_bf16.h>
#include <string.h>

// Problem constants
#define NROWS    4096
#define NBR      64
#define NODE_DIM 172
#define EDGE_DIM 172
#define TIME_DIM 100
#define OUT_DIM  272
#define KEY_DIM  444          // NODE+EDGE+TIME
#define KPAD     448          // KEY_DIM padded; row stride 896B (7*128 -> swizzle-closed)
#define QK_PAD   320          // OUT_DIM padded; row stride 640B
#define N_HEADS  8
#define HEAD_DIM 34

typedef __attribute__((ext_vector_type(8))) short short8_t;  // 8 bf16 in 4 VGPRs
typedef __attribute__((ext_vector_type(4))) float f32x4;

__device__ inline short f2b(float x) {          // fp32 -> bf16 (RNE), scalar one-offs
  unsigned u = __builtin_bit_cast(unsigned, x);
  unsigned r = (u + 0x7fffu + ((u >> 16) & 1u)) >> 16;
  return (short)r;
}

__device__ inline unsigned pk2(float lo, float hi) {  // v_cvt_pk_bf16_f32 via HIP API
  __hip_bfloat162 h = __float22bfloat162_rn(make_float2(lo, hi));
  unsigned u;
  memcpy(&u, &h, 4);                              // bit-identical, reg move after opt
  return u;
}

// Zero cols K0..KP-1 ((KP-K0)*2 must be a multiple of 8).
template<int ROWS, int KP, int K0>
__device__ inline void pad_rows(char* A, int t) {
  constexpr int NC8 = (KP - K0) / 4;
  constexpr int LPR = 512 / ROWS;
  int r = t / LPR;
  int j = t % LPR;
  char* Arow = A + r * (2 * KP);
  int swz = (r & 7) << 4;
  uint2 zz; zz.x = 0; zz.y = 0;
  for (int c8 = j; c8 < NC8; c8 += LPR)
    *(uint2*)(Arow + ((2 * K0 + 8 * c8) ^ swz)) = zz;
}

// One (MT*16)(M) x 16(N) output stripe. B (W) from global L2, A from swizzled LDS.
template<int MT, int KP, int NKK>
__device__ inline void gemm_tile(const short* __restrict__ Wrow, const char* A,
                                 int lr, int lk, f32x4* acc) {
#pragma unroll
  for (int kk = 0; kk < NKK; ++kk) {
    short8_t bfrag = *(const short8_t*)(Wrow + lr * KP + kk * 32 + lk * 8);
#pragma unroll
    for (int mt = 0; mt < MT; ++mt) {
      short8_t afrag = *(const short8_t*)(A + (mt * 16 + lr) * (2 * KP) +
                                          ((kk * 64 + lk * 16) ^ ((lr & 7) << 4)));
      acc[mt] = __builtin_amdgcn_mfma_f32_16x16x32_bf16(afrag, bfrag, acc[mt], 0, 0, 0);
    }
  }
}

// ---------------- kernel 0: weight conversion fp32 -> padded bf16 ----------------
__global__ void convert_w(const float* __restrict__ Wkv, const float* __restrict__ Wq,
                          const float* __restrict__ Wo, short* __restrict__ wq_b,
                          short* __restrict__ wo_b, short* __restrict__ wkt,
                          short* __restrict__ wvh) {
  int i = blockIdx.x * 256 + threadIdx.x;
  if (i < OUT_DIM * QK_PAD) {
    int r = i / QK_PAD, c = i - r * QK_PAD;
    wq_b[i] = (c < OUT_DIM) ? f2b(Wq[r * OUT_DIM + c]) : (short)0;
    wo_b[i] = (c < OUT_DIM) ? f2b(Wo[r * OUT_DIM + c]) : (short)0;
  }
  // Wkt[h][n=448][d=64] = W_KV[h*34+d][n]  (d>=34 or n>=444 -> 0)
  if (i < N_HEADS * 448 * 64) {
    int h = i / 28672;
    int rem = i - h * 28672;
    int n = rem >> 6, d = rem & 63;
    wkt[i] = (n < KEY_DIM && d < HEAD_DIM) ? f2b(Wkv[(h * HEAD_DIM + d) * KEY_DIM + n])
                                           : (short)0;
  }
  // Wvh[h][c'=48][k=448] = W_KV[272 + h*34 + c'][k]  (c'>=34 or k>=444 -> 0)
  if (i < N_HEADS * 48 * 448) {
    int h = i / 21504;
    int rem = i - h * 21504;
    int cp = rem / 448, k = rem - cp * 448;
    wvh[i] = (cp < HEAD_DIM && k < KEY_DIM)
                 ? f2b(Wkv[(OUT_DIM + h * HEAD_DIM + cp) * KEY_DIM + k])
                 : (short)0;
  }
}

// ---------------- kernel 1: Q = R@Wq^T ; Qt = (1/sqrt34) Qh@Wk  (16 rows/block) --------
__global__ __launch_bounds__(512) void q_qt(const float* __restrict__ node_feat,
                                            const float* __restrict__ time_feat,
                                            const short* __restrict__ Wq,
                                            const short* __restrict__ Wkt,
                                            short* __restrict__ Qtg) {
  __shared__ char Rlds[16 * 640];    // 10,240 B
  __shared__ char Qp[16 * 1024];     // 16,384 B
  int rb = blockIdx.x * 16, t = threadIdx.x;
  {
    int r = t >> 5, j = t & 31;      // 32 lanes per row
    const float4* pn = (const float4*)(node_feat + (size_t)(rb + r) * NODE_DIM);
    const float4* pt = (const float4*)(time_feat + (size_t)(rb + r) * TIME_DIM);
    float4 vn[2], vt4;
    int in_[2], it_;
#pragma unroll
    for (int i = 0; i < 2; ++i) { int f = j + 32 * i; in_[i] = f > 42 ? 42 : f; vn[i] = pn[in_[i]]; }
    it_ = j > 24 ? 24 : j; vt4 = pt[it_];
    char* Arow = Rlds + r * 640;
    int swz = (r & 7) << 4;
#pragma unroll
    for (int i = 0; i < 2; ++i) {
      uint2 w; w.x = pk2(vn[i].x, vn[i].y); w.y = pk2(vn[i].z, vn[i].w);
      *(uint2*)(Arow + ((8 * in_[i]) ^ swz)) = w;
    }
    {
      uint2 w; w.x = pk2(vt4.x, vt4.y); w.y = pk2(vt4.z, vt4.w);
      *(uint2*)(Arow + ((344 + 8 * it_) ^ swz)) = w;
    }
    if (j < 12) { uint2 zz; zz.x = 0; zz.y = 0; *(uint2*)(Arow + ((544 + 8 * j) ^ swz)) = zz; }
  }
  {
    uint4 zz; zz.x = 0; zz.y = 0; zz.z = 0; zz.w = 0;
    for (int i = t; i < 1024; i += 512) ((uint4*)Qp)[i] = zz;
  }
  __syncthreads();
  int wave = t >> 6, lane = t & 63, lr = lane & 15, lk = lane >> 4;
  f32x4 z = {0.f, 0.f, 0.f, 0.f};

  // GEMM1: Q = R @ Wq^T -> per-head packed Qp
  for (int nt = wave; nt < 17; nt += 8) {
    int nb = nt * 16;
    f32x4 acc[1] = {z};
    gemm_tile<1, QK_PAD, QK_PAD / 32>(Wq + nb * QK_PAD, Rlds, lr, lk, acc);
    int c = nb + lr;
    int h = c / HEAD_DIM, d = c - h * HEAD_DIM;
#pragma unroll
    for (int e = 0; e < 4; ++e) {
      int r = lk * 4 + e;
      *(short*)(Qp + r * 1024 + h * 128 + ((2 * d) ^ ((r & 7) << 4))) = f2b(acc[0][e]);
    }
  }
  __syncthreads();

  // GEMM2: Qt[b,h,k], scaled
  int h = wave;
  const short* Wh = Wkt + h * 28672;
  for (int nt = 0; nt < 28; ++nt) {
    f32x4 acc = z;
#pragma unroll
    for (int kk = 0; kk < 2; ++kk) {
      short8_t bfrag = *(const short8_t*)(Wh + (nt * 16 + lr) * 64 + kk * 32 + lk * 8);
      short8_t afrag = *(const short8_t*)(Qp + lr * 1024 + h * 128 +
                                          ((kk * 64 + lk * 16) ^ ((lr & 7) << 4)));
      acc = __builtin_amdgcn_mfma_f32_16x16x32_bf16(afrag, bfrag, acc, 0, 0, 0);
    }
#pragma unroll
    for (int e = 0; e < 4; ++e)
      Qtg[(size_t)(rb + lk * 4 + e) * 3584 + h * 448 + nt * 16 + lr] =
          f2b(acc[e] * 0.17149858514250882f);
  }
}

// ---------------- kernel 2: attn3 + asm-pinned batched staging loads ----------------
// Yh2 layout: [(h*14+kk2)][b][32 bf16] -> coalesced A-frag reads in out_ln2.
__global__ __launch_bounds__(512) void attn3(const float* __restrict__ nbr_node,
                                             const float* __restrict__ edge_feat,
                                             const float* __restrict__ nbr_time,
                                             const int* __restrict__ nbr_mask,
                                             const short* __restrict__ Qtg,
                                             short* __restrict__ Yh2) {
  __shared__ char Alds[64 * 896];                 // 57,344 B : Z bf16 swizzled
  __shared__ float Spart[2][64][8];               //  4,096 B
  __shared__ char Pb[16 * 128];                   //  2,048 B : P bf16 [16 rows][64 n] swz
  int b = blockIdx.x;
  int t = threadIdx.x;
  int wave = t >> 6, lane = t & 63, lr = lane & 15, lk = lane >> 4;
  int mpre = nbr_mask[(size_t)b * NBR + lane];

  // Staging: issue ALL 16 f32x4 loads, then pin their results live with an asm that
  // consumes them simultaneously, then convert+write.
  {
    int r = t >> 3, j = t & 7;
    const f32x4* pn = (const f32x4*)(nbr_node + (size_t)b * NBR * NODE_DIM) + (size_t)r * 43;
    const f32x4* pe = (const f32x4*)(edge_feat + (size_t)b * NBR * EDGE_DIM) + (size_t)r * 43;
    const f32x4* pt = (const f32x4*)(nbr_time + (size_t)b * NBR * TIME_DIM) + (size_t)r * 25;
    f32x4 vn[6], ve[6], vt4[4];
    int in_[6], it_[4];
#pragma unroll
    for (int i = 0; i < 6; ++i) { int f = j + 8 * i; in_[i] = f > 42 ? 42 : f; vn[i] = pn[in_[i]]; }
#pragma unroll
    for (int i = 0; i < 6; ++i) { ve[i] = pe[in_[i]]; }
#pragma unroll
    for (int i = 0; i < 4; ++i) { int f = j + 8 * i; it_[i] = f > 24 ? 24 : f; vt4[i] = pt[it_[i]]; }
    asm volatile("" :: "v"(vn[0]), "v"(vn[1]), "v"(vn[2]), "v"(vn[3]), "v"(vn[4]), "v"(vn[5]),
                       "v"(ve[0]), "v"(ve[1]), "v"(ve[2]), "v"(ve[3]), "v"(ve[4]), "v"(ve[5]),
                       "v"(vt4[0]), "v"(vt4[1]), "v"(vt4[2]), "v"(vt4[3])
                 : "memory");
    char* Arow = Alds + r * 896;
    int swz = (r & 7) << 4;
#pragma unroll
    for (int i = 0; i < 6; ++i) {
      uint2 w; w.x = pk2(vn[i][0], vn[i][1]); w.y = pk2(vn[i][2], vn[i][3]);
      *(uint2*)(Arow + ((8 * in_[i]) ^ swz)) = w;
    }
#pragma unroll
    for (int i = 0; i < 6; ++i) {
      uint2 w; w.x = pk2(ve[i][0], ve[i][1]); w.y = pk2(ve[i][2], ve[i][3]);
      *(uint2*)(Arow + ((344 + 8 * in_[i]) ^ swz)) = w;
    }
#pragma unroll
    for (int i = 0; i < 4; ++i) {
      uint2 w; w.x = pk2(vt4[i][0], vt4[i][1]); w.y = pk2(vt4[i][2], vt4[i][3]);
      *(uint2*)(Arow + ((688 + 8 * it_[i]) ^ swz)) = w;
    }
    if (j == 0) { uint2 zz; zz.x = 0; zz.y = 0; *(uint2*)(Arow + (888 ^ swz)) = zz; }
  }
  __syncthreads();

  f32x4 z = {0.f, 0.f, 0.f, 0.f};

  // scores: D[h][n] = sum_k Qt[h][k] Z[n][k]; wave = (ntile 0..3, khalf 0..1)
  {
    int ntw = wave & 3, kh = wave >> 2;
    f32x4 acc = z;
    const short* qrow = Qtg + (size_t)b * 3584 + (lr & 7) * 448;
    const char* zbase = Alds + (ntw * 16 + lr) * 896;
    int swz = (lr & 7) << 4;
#pragma unroll
    for (int k7 = 0; k7 < 7; ++k7) {
      int ke = (kh * 7 + k7) * 32 + lk * 8;        // element offset in [0,448)
      short8_t a = *(const short8_t*)(qrow + ke);
      short8_t bbv = *(const short8_t*)(zbase + ((2 * ke) ^ swz));
      acc = __builtin_amdgcn_mfma_f32_16x16x32_bf16(a, bbv, acc, 0, 0, 0);
    }
#pragma unroll
    for (int e = 0; e < 4; ++e) {
      int h = lk * 4 + e;
      if (h < 8) Spart[kh][ntw * 16 + lr][h] = acc[e];
    }
  }
  __syncthreads();

  // softmax: wave h, lane n (scale folded into Qt); write P as bf16 A-tile
  {
    int h = wave, n = lane;
    float s = Spart[0][n][h] + Spart[1][n][h];
    if (mpre == 0) s = -1e10f;
    float m = s;
#pragma unroll
    for (int off = 32; off >= 1; off >>= 1) m = fmaxf(m, __shfl_xor(m, off));
    float e = __expf(s - m);
    float sum = e;
#pragma unroll
    for (int off = 32; off >= 1; off >>= 1) sum += __shfl_xor(sum, off);
    int off2 = (2 * n) ^ ((h & 7) << 4);
    *(short*)(Pb + h * 128 + off2) = f2b(e / sum);
    *(short*)(Pb + (h + 8) * 128 + off2) = 0;     // zero pad rows 8..15
  }
  __syncthreads();

  // Yh[h][k] = sum_n P[h][n] Z[n][k] via MFMA: M=16(h-pad) N=448 K=64.
  for (int vt = wave; vt < 28; vt += 8) {
    int vb = vt * 16;
    f32x4 acc = z;
    int colb = 2 * (vb + lr);                      // byte offset of the k-column
#pragma unroll
    for (int kk = 0; kk < 2; ++kk) {
      short8_t pa = *(const short8_t*)(Pb + lr * 128 +
                                       ((kk * 64 + lk * 16) ^ ((lr & 7) << 4)));
      const char* zb_base = Alds + (kk * 32 + lk * 8) * 896;
      short8_t zb;
#pragma unroll
      for (int j = 0; j < 8; ++j)
        zb[j] = *(const short*)(zb_base + j * 896 + (colb ^ (j << 4)));
      acc = __builtin_amdgcn_mfma_f32_16x16x32_bf16(pa, zb, acc, 0, 0, 0);
    }
    if (lk < 2) {
      int k = vb + lr, kk2 = k >> 5, kp = k & 31;
#pragma unroll
      for (int e = 0; e < 4; ++e) {
        int h = lk * 4 + e;
        Yh2[((size_t)(h * 14 + kk2) * 4096 + b) * 32 + kp] = f2b(acc[e]);
      }
    }
  }
}

// ---------------- kernel 3: O = Yh.Wvh^T ; out = LN(O @ W_O^T + b_O + R)  (16 rows) ----
__global__ __launch_bounds__(512) void out_ln2(const short* __restrict__ Yh2,
                                               const short* __restrict__ Wvh,
                                               const short* __restrict__ Wo,
                                               const float* __restrict__ bO,
                                               const float* __restrict__ node_feat,
                                               const float* __restrict__ time_feat,
                                               const float* __restrict__ gamma,
                                               const float* __restrict__ beta,
                                               float* __restrict__ out) {
  __shared__ char Alds[16 * 640];          // 10,240 B : O tile bf16 swizzled
  __shared__ float X[16 * 276];            // 17,664 B
  int rb = blockIdx.x * 16;
  int t = threadIdx.x;
  int wave = t >> 6, lane = t & 63, lr = lane & 15, lk = lane >> 4;
  pad_rows<16, QK_PAD, OUT_DIM>(Alds, t);  // zero cols 272..319
  f32x4 z = {0.f, 0.f, 0.f, 0.f};

  // Phase A: O[r][h*34+cl] = sum_k Yh[r][h][k] Wvh[h][cl][k]; 24 (h,nt) pairs / 8 waves
  for (int p = wave; p < 24; p += 8) {
    int h = p / 3, nt = p - h * 3;
    f32x4 acc = z;
#pragma unroll
    for (int kk = 0; kk < 14; ++kk) {
      short8_t bfrag = *(const short8_t*)(Wvh + h * 21504 + (nt * 16 + lr) * 448 +
                                          kk * 32 + lk * 8);
      short8_t afrag = *(const short8_t*)(
          Yh2 + ((size_t)(h * 14 + kk) * 4096 + rb + lr) * 32 + lk * 8);
      acc = __builtin_amdgcn_mfma_f32_16x16x32_bf16(afrag, bfrag, acc, 0, 0, 0);
    }
    int cl = nt * 16 + lr;
    if (cl < HEAD_DIM) {
      int c = h * HEAD_DIM + cl;
#pragma unroll
      for (int e = 0; e < 4; ++e) {
        int r = lk * 4 + e;
        *(short*)(Alds + r * 640 + ((2 * c) ^ ((r & 7) << 4))) = f2b(acc[e]);
      }
    }
  }
  __syncthreads();

  // Phase B: proj + bias + residual into X
  for (int nt = wave; nt < 17; nt += 8) {
    int nb = nt * 16;
    f32x4 acc[1] = {z};
    gemm_tile<1, QK_PAD, QK_PAD / 32>(Wo + nb * QK_PAD, Alds, lr, lk, acc);
    int c = nb + lr;
    float bo = bO[c];
#pragma unroll
    for (int e = 0; e < 4; ++e) {
      int r = lk * 4 + e;
      int gr = rb + r;
      float Rv = (c < NODE_DIM) ? node_feat[(size_t)gr * NODE_DIM + c]
                                : time_feat[(size_t)gr * TIME_DIM + (c - NODE_DIM)];
      X[r * 276 + c] = acc[0][e] + bo + Rv;
    }
  }
  __syncthreads();

  // LayerNorm: 32 lanes per row
  int row = t >> 5, j = t & 31;
  float s1 = 0.f, s2 = 0.f;
  for (int c = j; c < OUT_DIM; c += 32) {
    float v = X[row * 276 + c];
    s1 += v; s2 += v * v;
  }
#pragma unroll
  for (int off = 16; off >= 1; off >>= 1) {
    s1 += __shfl_xor(s1, off);
    s2 += __shfl_xor(s2, off);
  }
  float mu = s1 * (1.f / OUT_DIM);
  float var = s2 * (1.f / OUT_DIM) - mu * mu;
  float inv = rsqrtf(fmaxf(var, 0.f) + 1e-5f);
  int gr = rb + row;
  for (int c = j; c < OUT_DIM; c += 32) {
    float v = X[row * 276 + c];
    out[(size_t)gr * OUT_DIM + c] = (v - mu) * inv * gamma[c] + beta[c];
  }
}

extern "C" void kernel_launch(void* const* d_in, const int* in_sizes, int n_in,
                              void* d_out, int out_size, void* d_ws, size_t ws_size,
                              hipStream_t stream) {
  const float* node_feat = (const float*)d_in[0];
  const float* time_feat = (const float*)d_in[1];
  const float* edge_feat = (const float*)d_in[2];
  const float* nbr_node  = (const float*)d_in[3];
  const float* nbr_time  = (const float*)d_in[4];
  const int*   nbr_mask  = (const int*)d_in[5];
  const float* W_Q   = (const float*)d_in[6];
  const float* W_KV  = (const float*)d_in[7];
  const float* W_O   = (const float*)d_in[8];
  const float* b_O   = (const float*)d_in[9];
  const float* gamma = (const float*)d_in[10];
  const float* beta  = (const float*)d_in[11];
  float* out = (float*)d_out;
  char* ws = (char*)d_ws;

  // ws layout (requires ~59.9 MB; ws >= 64.8 MB confirmed in round 4):
  short* wq_b = (short*)(ws);                     // 272*320*2   = 174,080
  short* wo_b = (short*)(ws + 174080);            // 174,080 -> 348,160
  short* wvh  = (short*)(ws + 348160);            // 8*48*448*2  = 344,064 -> 692,224
  short* wkt  = (short*)(ws + 692224);            // 8*448*64*2  = 458,752 -> 1,150,976
  short* Qtg  = (short*)(ws + 1150976);           // 4096*3584*2 = 29,360,128 -> 30,511,104
  short* Yh2  = (short*)(ws + 30511104);          // 29,360,128 -> 59,871,232

  convert_w<<<896, 256, 0, stream>>>(W_KV, W_Q, W_O, wq_b, wo_b, wkt, wvh);
  q_qt<<<NROWS / 16, 512, 0, stream>>>(node_feat, time_feat, wq_b, wkt, Qtg);
  attn3<<<NROWS, 512, 0, stream>>>(nbr_node, edge_feat, nbr_time, nbr_mask, Qtg, Yh2);
  out_ln2<<<NROWS / 16, 512, 0, stream>>>(Yh2, wvh, wo_b, b_O, node_feat, time_feat,
                                          gamma, beta, out);
}